// Round 1
// baseline (10.432 us; speedup 1.0000x reference)
//
#include <hip/hip_runtime.h>
#include <hip/hip_bf16.h>

// Reference collapses analytically:
//   h0 = 0, and h_new = tanh(bilinear(x, A, h)) is homogeneous in h
//   => h_T == 0 exactly for all finite inputs
//   => logits[b,c] = b_out[c]; out[b,c] = sigmoid(b_out[c]).
// So the kernel just broadcasts sigmoid(b_out) over the batch.

#define B_SZ 4096
#define C_SZ 5

__global__ void Model_33285996544307_kernel(const float* __restrict__ b_out,
                                            float* __restrict__ out,
                                            int n) {
    // Compute sigmoid(b_out[c]) once per thread from the 5-element vector
    // (L2-cached broadcast load; negligible).
    int i = blockIdx.x * blockDim.x + threadIdx.x;
    if (i < n) {
        int c = i % C_SZ;
        float v = b_out[c];
        out[i] = 1.0f / (1.0f + __expf(-v));
    }
}

extern "C" void kernel_launch(void* const* d_in, const int* in_sizes, int n_in,
                              void* d_out, int out_size, void* d_ws, size_t ws_size,
                              hipStream_t stream) {
    // Inputs (setup_inputs order): words, batch_size, emb, A, W_out, b_out
    const float* b_out = (const float*)d_in[5];
    float* out = (float*)d_out;

    int n = out_size;  // B*C = 20480
    int block = 256;
    int grid = (n + block - 1) / block;
    Model_33285996544307_kernel<<<grid, block, 0, stream>>>(b_out, out, n);
}